// Round 1
// baseline (350.080 us; speedup 1.0000x reference)
//
#include <hip/hip_runtime.h>
#include <hip/hip_bf16.h>

#define DIM 128
#define SEQ 8192
#define BR 64
#define BC 64
#define KSTR 136   // K LDS row stride (elems): 272B rows -> 16B-aligned frags, 2-way banks
#define VSTR 72    // V^T LDS row stride: 144B rows -> 16B-aligned frags
#define PSTR 72
#define SCALE 0.08838834764831845f  // 1/sqrt(128)

typedef __attribute__((ext_vector_type(8))) short short8;
typedef __attribute__((ext_vector_type(4))) float f32x4;

__device__ __forceinline__ unsigned short f2bf(float f) {
  return __builtin_bit_cast(unsigned short, __float2bfloat16(f));
}

__global__ __launch_bounds__(256, 1) void attn_fwd(
    const float* __restrict__ Q, const float* __restrict__ K,
    const float* __restrict__ V, float* __restrict__ O) {
  __shared__ __align__(16) unsigned short kt[BC * KSTR];      // K tile [kv][d], bf16
  __shared__ __align__(16) unsigned short vt[DIM * VSTR];     // V tile transposed [d][kv], bf16
  __shared__ __align__(16) unsigned short pt[4][16 * PSTR];   // per-wave P tile [qrow][kv]

  const int tid  = threadIdx.x;
  const int wave = tid >> 6;
  const int lane = tid & 63;
  const int l15  = lane & 15;
  const int quad = lane >> 4;

  const int qbase = blockIdx.x * BR + wave * 16;  // this wave's 16 Q rows

  // Q fragments in registers: A[m=l15][k=c*32 + quad*8 + j]
  short8 qf[4];
  {
    const float* qrow = Q + (size_t)(qbase + l15) * DIM + quad * 8;
    #pragma unroll
    for (int c = 0; c < 4; c++) {
      short8 v;
      #pragma unroll
      for (int j = 0; j < 8; j++) v[j] = (short)f2bf(qrow[c * 32 + j]);
      qf[c] = v;
    }
  }

  float m_i[4], l_i[4];
  f32x4 o[8];
  const f32x4 fzero = {0.f, 0.f, 0.f, 0.f};
  #pragma unroll
  for (int r = 0; r < 4; r++) { m_i[r] = -__builtin_inff(); l_i[r] = 0.f; }
  #pragma unroll
  for (int d = 0; d < 8; d++) o[d] = fzero;

  unsigned short* pw = &pt[wave][0];

  for (int kv0 = 0; kv0 < SEQ; kv0 += BC) {
    __syncthreads();  // prior tile fully consumed before overwrite
    // ---- stage K tile [BC][DIM] fp32 -> bf16 LDS (row-major) ----
    #pragma unroll
    for (int i = 0; i < 8; i++) {
      int idx = i * 256 + tid;
      int r  = idx >> 5;
      int c4 = (idx & 31) << 2;
      const float* src = K + (size_t)(kv0 + r) * DIM + c4;
      ushort4 u;
      u.x = f2bf(src[0]); u.y = f2bf(src[1]);
      u.z = f2bf(src[2]); u.w = f2bf(src[3]);
      *(ushort4*)&kt[r * KSTR + c4] = u;
    }
    // ---- stage V tile transposed: vt[d][kv] ----
    #pragma unroll
    for (int i = 0; i < 8; i++) {
      int idx = i * 256 + tid;
      int c = idx & 127;       // d index
      int g = idx >> 7;        // kv group of 4
      const float* src = V + (size_t)(kv0 + 4 * g) * DIM + c;
      ushort4 u;
      u.x = f2bf(src[0]);        u.y = f2bf(src[DIM]);
      u.z = f2bf(src[2 * DIM]);  u.w = f2bf(src[3 * DIM]);
      *(ushort4*)&vt[c * VSTR + 4 * g] = u;
    }
    __syncthreads();

    // ---- S = Q K^T : 4 col-blocks x 4 K-chunks ----
    f32x4 s[4];
    #pragma unroll
    for (int blk = 0; blk < 4; blk++) {
      f32x4 acc = fzero;
      const unsigned short* kr = &kt[(blk * 16 + l15) * KSTR + quad * 8];
      #pragma unroll
      for (int c = 0; c < 4; c++)
        acc = __builtin_amdgcn_mfma_f32_16x16x32_bf16(
            qf[c], *(const short8*)&kr[c * 32], acc, 0, 0, 0);
      s[blk] = acc;
    }

    // ---- online softmax (row = quad*4 + r, col = blk*16 + l15) ----
    #pragma unroll
    for (int r = 0; r < 4; r++) {
      float v = fmaxf(fmaxf(s[0][r], s[1][r]), fmaxf(s[2][r], s[3][r])) * SCALE;
      v = fmaxf(v, __shfl_xor(v, 1));
      v = fmaxf(v, __shfl_xor(v, 2));
      v = fmaxf(v, __shfl_xor(v, 4));
      v = fmaxf(v, __shfl_xor(v, 8));
      float mnew  = fmaxf(m_i[r], v);
      float alpha = __expf(m_i[r] - mnew);
      m_i[r] = mnew;
      float sum = 0.f;
      #pragma unroll
      for (int blk = 0; blk < 4; blk++) {
        float p = __expf(s[blk][r] * SCALE - mnew);
        sum += p;
        pw[(quad * 4 + r) * PSTR + blk * 16 + l15] = f2bf(p);
      }
      sum += __shfl_xor(sum, 1);
      sum += __shfl_xor(sum, 2);
      sum += __shfl_xor(sum, 4);
      sum += __shfl_xor(sum, 8);
      l_i[r] = l_i[r] * alpha + sum;
      #pragma unroll
      for (int d = 0; d < 8; d++) o[d][r] *= alpha;
    }

    // ---- O += P V : P re-read in A-layout from per-wave LDS tile ----
    short8 ap0 = *(const short8*)&pw[l15 * PSTR + quad * 8];
    short8 ap1 = *(const short8*)&pw[l15 * PSTR + 32 + quad * 8];
    #pragma unroll
    for (int d = 0; d < 8; d++) {
      const unsigned short* vr = &vt[(d * 16 + l15) * VSTR + quad * 8];
      o[d] = __builtin_amdgcn_mfma_f32_16x16x32_bf16(
          ap0, *(const short8*)&vr[0], o[d], 0, 0, 0);
      o[d] = __builtin_amdgcn_mfma_f32_16x16x32_bf16(
          ap1, *(const short8*)&vr[32], o[d], 0, 0, 0);
    }
  }

  // ---- epilogue: normalize and store ----
  #pragma unroll
  for (int r = 0; r < 4; r++) {
    float inv = 1.f / l_i[r];
    float* orow = O + (size_t)(qbase + quad * 4 + r) * DIM + l15;
    #pragma unroll
    for (int d = 0; d < 8; d++) orow[d * 16] = o[d][r] * inv;
  }
}

extern "C" void kernel_launch(void* const* d_in, const int* in_sizes, int n_in,
                              void* d_out, int out_size, void* d_ws, size_t ws_size,
                              hipStream_t stream) {
  const float* Q = (const float*)d_in[0];
  const float* K = (const float*)d_in[1];
  const float* V = (const float*)d_in[2];
  float* O = (float*)d_out;
  hipLaunchKernelGGL(attn_fwd, dim3(SEQ / BR), dim3(256), 0, stream, Q, K, V, O);
}

// Round 2
// 206.893 us; speedup vs baseline: 1.6921x; 1.6921x over previous
//
#include <hip/hip_runtime.h>
#include <hip/hip_bf16.h>

#define DIM 128
#define SEQ 8192
#define BR 64
#define BC 64
#define NSPLIT 8
#define SPLITLEN (SEQ / NSPLIT)          // 1024
#define QT (SEQ / BR)                    // 128
#define OP_ELEMS ((size_t)QT * NSPLIT * BR * DIM)   // 8388608 floats
#define ML_ELEMS ((size_t)QT * NSPLIT * BR * 2)     // 131072 floats
#define SCALE 0.08838834764831845f       // 1/sqrt(128)

typedef __attribute__((ext_vector_type(8))) short short8;
typedef __attribute__((ext_vector_type(4))) float f32x4;

__device__ __forceinline__ unsigned short f2bf(float f) {
  return __builtin_bit_cast(unsigned short, __float2bfloat16(f));
}

// ---------------- split-KV main kernel ----------------
// LDS: kt 64x128 (16 KB) + vt 128x64 (16 KB) + pt 4x16x64 (8 KB) = 40960 B
// -> exactly 4 blocks/CU. All tiles XOR-swizzled in 8-elem chunks: chunk ^= (row&7).
__global__ __launch_bounds__(256, 4) void attn_split(
    const float* __restrict__ Q, const float* __restrict__ K,
    const float* __restrict__ V, float* __restrict__ ws) {
  __shared__ __align__(16) unsigned short kt[BC * 128];   // [kv][d] swizzled
  __shared__ __align__(16) unsigned short vt[DIM * 64];   // [d][kv] swizzled
  __shared__ __align__(16) unsigned short pt[4][16 * 64]; // per-wave [qrow][kv] swizzled

  const int tid  = threadIdx.x;
  const int wave = tid >> 6;
  const int lane = tid & 63;
  const int l15  = lane & 15;
  const int quad = lane >> 4;
  const int sw   = l15 & 7;

  const int qtile = blockIdx.x;
  const int split = blockIdx.y;
  const int qbase = qtile * BR + wave * 16;

  // Q fragments: A[m=l15][k=c*32 + quad*8 + j]
  short8 qf[4];
  {
    const float* qrow = Q + (size_t)(qbase + l15) * DIM + quad * 8;
    #pragma unroll
    for (int c = 0; c < 4; c++) {
      short8 v;
      #pragma unroll
      for (int j = 0; j < 8; j++) v[j] = (short)f2bf(qrow[c * 32 + j]);
      qf[c] = v;
    }
  }

  float m_i[4], l_i[4];
  f32x4 o[8];
  const f32x4 fzero = {0.f, 0.f, 0.f, 0.f};
  #pragma unroll
  for (int r = 0; r < 4; r++) { m_i[r] = -__builtin_inff(); l_i[r] = 0.f; }
  #pragma unroll
  for (int d = 0; d < 8; d++) o[d] = fzero;

  unsigned short* pw = &pt[wave][0];

  const int kv_lo = split * SPLITLEN;
  const int kv_hi = kv_lo + SPLITLEN;
  for (int kv0 = kv_lo; kv0 < kv_hi; kv0 += BC) {
    __syncthreads();
    // ---- stage K tile [64][128] fp32 -> bf16, swizzled ----
    #pragma unroll
    for (int i = 0; i < 8; i++) {
      int idx = i * 256 + tid;
      int r  = idx >> 5;
      int c4 = (idx & 31) << 2;
      int g  = c4 >> 3;
      const float* src = K + (size_t)(kv0 + r) * DIM + c4;
      ushort4 u;
      u.x = f2bf(src[0]); u.y = f2bf(src[1]);
      u.z = f2bf(src[2]); u.w = f2bf(src[3]);
      *(ushort4*)&kt[r * 128 + ((g ^ (r & 7)) << 3) + (c4 & 7)] = u;
    }
    // ---- stage V tile transposed [d][kv], swizzled ----
    #pragma unroll
    for (int i = 0; i < 8; i++) {
      int idx = i * 256 + tid;
      int c  = idx & 127;      // d
      int gi = idx >> 7;       // kv group of 4
      int ch = gi >> 1;
      const float* src = V + (size_t)(kv0 + 4 * gi) * DIM + c;
      ushort4 u;
      u.x = f2bf(src[0]);        u.y = f2bf(src[DIM]);
      u.z = f2bf(src[2 * DIM]);  u.w = f2bf(src[3 * DIM]);
      *(ushort4*)&vt[c * 64 + ((ch ^ (c & 7)) << 3) + (gi & 1) * 4] = u;
    }
    __syncthreads();

    // ---- S = Q K^T ----
    f32x4 s[4];
    #pragma unroll
    for (int blk = 0; blk < 4; blk++) {
      f32x4 acc = fzero;
      int base = (blk * 16 + l15) * 128;
      #pragma unroll
      for (int c = 0; c < 4; c++) {
        int g = 4 * c + quad;
        acc = __builtin_amdgcn_mfma_f32_16x16x32_bf16(
            qf[c], *(const short8*)&kt[base + ((g ^ sw) << 3)], acc, 0, 0, 0);
      }
      s[blk] = acc;
    }

    // ---- online softmax (row = quad*4+r, col = blk*16 + l15) ----
    #pragma unroll
    for (int r = 0; r < 4; r++) {
      float v = fmaxf(fmaxf(s[0][r], s[1][r]), fmaxf(s[2][r], s[3][r])) * SCALE;
      v = fmaxf(v, __shfl_xor(v, 1));
      v = fmaxf(v, __shfl_xor(v, 2));
      v = fmaxf(v, __shfl_xor(v, 4));
      v = fmaxf(v, __shfl_xor(v, 8));
      float mnew  = fmaxf(m_i[r], v);
      float alpha = __expf(m_i[r] - mnew);
      m_i[r] = mnew;
      int prow = quad * 4 + r;
      int swp  = prow & 7;
      float sum = 0.f;
      #pragma unroll
      for (int blk = 0; blk < 4; blk++) {
        float p = __expf(s[blk][r] * SCALE - mnew);
        sum += p;
        int ch = 2 * blk + (l15 >> 3);
        pw[prow * 64 + ((ch ^ swp) << 3) + (l15 & 7)] = f2bf(p);
      }
      sum += __shfl_xor(sum, 1);
      sum += __shfl_xor(sum, 2);
      sum += __shfl_xor(sum, 4);
      sum += __shfl_xor(sum, 8);
      l_i[r] = l_i[r] * alpha + sum;
      #pragma unroll
      for (int d = 0; d < 8; d++) o[d][r] *= alpha;
    }

    // ---- O += P V ----
    short8 ap0 = *(const short8*)&pw[l15 * 64 + ((quad ^ sw) << 3)];
    short8 ap1 = *(const short8*)&pw[l15 * 64 + (((4 + quad) ^ sw) << 3)];
    #pragma unroll
    for (int d = 0; d < 8; d++) {
      int base = (d * 16 + l15) * 64;
      o[d] = __builtin_amdgcn_mfma_f32_16x16x32_bf16(
          ap0, *(const short8*)&vt[base + ((quad ^ sw) << 3)], o[d], 0, 0, 0);
      o[d] = __builtin_amdgcn_mfma_f32_16x16x32_bf16(
          ap1, *(const short8*)&vt[base + (((4 + quad) ^ sw) << 3)], o[d], 0, 0, 0);
    }
  }

  // ---- epilogue: store unnormalized O + (m,l) to workspace ----
  float* op  = ws + (size_t)(qtile * NSPLIT + split) * BR * DIM;
  float* mlp = ws + OP_ELEMS + (size_t)(qtile * NSPLIT + split) * BR * 2;
  #pragma unroll
  for (int r = 0; r < 4; r++) {
    int row = wave * 16 + quad * 4 + r;
    float* orow = op + (size_t)row * DIM + l15;
    #pragma unroll
    for (int d = 0; d < 8; d++) orow[d * 16] = o[d][r];
    if (l15 == 0) { mlp[row * 2] = m_i[r]; mlp[row * 2 + 1] = l_i[r]; }
  }
}

// ---------------- combine kernel ----------------
__global__ __launch_bounds__(256) void attn_combine(
    const float* __restrict__ ws, float* __restrict__ O) {
  const int tid  = threadIdx.x;
  const int rloc = tid >> 5;
  const int c4   = (tid & 31) << 2;
  const int rg   = blockIdx.x * 8 + rloc;
  const int qt   = rg >> 6;
  const int row  = rg & 63;
  const float* ml = ws + OP_ELEMS;

  float m[NSPLIT], l[NSPLIT];
  float mmax = -__builtin_inff();
  #pragma unroll
  for (int s = 0; s < NSPLIT; s++) {
    const float* p = ml + (size_t)((qt * NSPLIT + s) * BR + row) * 2;
    m[s] = p[0]; l[s] = p[1];
    mmax = fmaxf(mmax, m[s]);
  }
  float denom = 0.f, w[NSPLIT];
  #pragma unroll
  for (int s = 0; s < NSPLIT; s++) {
    w[s] = __expf(m[s] - mmax);
    denom += l[s] * w[s];
  }
  float4 acc = {0.f, 0.f, 0.f, 0.f};
  #pragma unroll
  for (int s = 0; s < NSPLIT; s++) {
    const float4 v = *(const float4*)&ws[(size_t)((qt * NSPLIT + s) * BR + row) * DIM + c4];
    acc.x += w[s] * v.x; acc.y += w[s] * v.y;
    acc.z += w[s] * v.z; acc.w += w[s] * v.w;
  }
  float inv = 1.f / denom;
  float4 out = {acc.x * inv, acc.y * inv, acc.z * inv, acc.w * inv};
  *(float4*)&O[(size_t)rg * DIM + c4] = out;
}

// ---------------- fallback (round-1 kernel, used only if ws too small) ----------------
#define KSTR 136
#define VSTR 72
#define PSTR 72
__global__ __launch_bounds__(256, 1) void attn_fwd_fb(
    const float* __restrict__ Q, const float* __restrict__ K,
    const float* __restrict__ V, float* __restrict__ O) {
  __shared__ __align__(16) unsigned short kt[BC * KSTR];
  __shared__ __align__(16) unsigned short vt[DIM * VSTR];
  __shared__ __align__(16) unsigned short pt[4][16 * PSTR];
  const int tid = threadIdx.x, wave = tid >> 6, lane = tid & 63;
  const int l15 = lane & 15, quad = lane >> 4;
  const int qbase = blockIdx.x * BR + wave * 16;
  short8 qf[4];
  {
    const float* qrow = Q + (size_t)(qbase + l15) * DIM + quad * 8;
    #pragma unroll
    for (int c = 0; c < 4; c++) {
      short8 v;
      #pragma unroll
      for (int j = 0; j < 8; j++) v[j] = (short)f2bf(qrow[c * 32 + j]);
      qf[c] = v;
    }
  }
  float m_i[4], l_i[4];
  f32x4 o[8];
  const f32x4 fzero = {0.f, 0.f, 0.f, 0.f};
  #pragma unroll
  for (int r = 0; r < 4; r++) { m_i[r] = -__builtin_inff(); l_i[r] = 0.f; }
  #pragma unroll
  for (int d = 0; d < 8; d++) o[d] = fzero;
  unsigned short* pw = &pt[wave][0];
  for (int kv0 = 0; kv0 < SEQ; kv0 += BC) {
    __syncthreads();
    #pragma unroll
    for (int i = 0; i < 8; i++) {
      int idx = i * 256 + tid;
      int r = idx >> 5, c4 = (idx & 31) << 2;
      const float* src = K + (size_t)(kv0 + r) * DIM + c4;
      ushort4 u;
      u.x = f2bf(src[0]); u.y = f2bf(src[1]); u.z = f2bf(src[2]); u.w = f2bf(src[3]);
      *(ushort4*)&kt[r * KSTR + c4] = u;
    }
    #pragma unroll
    for (int i = 0; i < 8; i++) {
      int idx = i * 256 + tid;
      int c = idx & 127, g = idx >> 7;
      const float* src = V + (size_t)(kv0 + 4 * g) * DIM + c;
      ushort4 u;
      u.x = f2bf(src[0]); u.y = f2bf(src[DIM]); u.z = f2bf(src[2 * DIM]); u.w = f2bf(src[3 * DIM]);
      *(ushort4*)&vt[c * VSTR + 4 * g] = u;
    }
    __syncthreads();
    f32x4 s[4];
    #pragma unroll
    for (int blk = 0; blk < 4; blk++) {
      f32x4 acc = fzero;
      const unsigned short* kr = &kt[(blk * 16 + l15) * KSTR + quad * 8];
      #pragma unroll
      for (int c = 0; c < 4; c++)
        acc = __builtin_amdgcn_mfma_f32_16x16x32_bf16(qf[c], *(const short8*)&kr[c * 32], acc, 0, 0, 0);
      s[blk] = acc;
    }
    #pragma unroll
    for (int r = 0; r < 4; r++) {
      float v = fmaxf(fmaxf(s[0][r], s[1][r]), fmaxf(s[2][r], s[3][r])) * SCALE;
      v = fmaxf(v, __shfl_xor(v, 1)); v = fmaxf(v, __shfl_xor(v, 2));
      v = fmaxf(v, __shfl_xor(v, 4)); v = fmaxf(v, __shfl_xor(v, 8));
      float mnew = fmaxf(m_i[r], v);
      float alpha = __expf(m_i[r] - mnew);
      m_i[r] = mnew;
      float sum = 0.f;
      #pragma unroll
      for (int blk = 0; blk < 4; blk++) {
        float p = __expf(s[blk][r] * SCALE - mnew);
        sum += p;
        pw[(quad * 4 + r) * PSTR + blk * 16 + l15] = f2bf(p);
      }
      sum += __shfl_xor(sum, 1); sum += __shfl_xor(sum, 2);
      sum += __shfl_xor(sum, 4); sum += __shfl_xor(sum, 8);
      l_i[r] = l_i[r] * alpha + sum;
      #pragma unroll
      for (int d = 0; d < 8; d++) o[d][r] *= alpha;
    }
    short8 ap0 = *(const short8*)&pw[l15 * PSTR + quad * 8];
    short8 ap1 = *(const short8*)&pw[l15 * PSTR + 32 + quad * 8];
    #pragma unroll
    for (int d = 0; d < 8; d++) {
      const unsigned short* vr = &vt[(d * 16 + l15) * VSTR + quad * 8];
      o[d] = __builtin_amdgcn_mfma_f32_16x16x32_bf16(ap0, *(const short8*)&vr[0], o[d], 0, 0, 0);
      o[d] = __builtin_amdgcn_mfma_f32_16x16x32_bf16(ap1, *(const short8*)&vr[32], o[d], 0, 0, 0);
    }
  }
  #pragma unroll
  for (int r = 0; r < 4; r++) {
    float inv = 1.f / l_i[r];
    float* orow = O + (size_t)(qbase + quad * 4 + r) * DIM + l15;
    #pragma unroll
    for (int d = 0; d < 8; d++) orow[d * 16] = o[d][r] * inv;
  }
}

extern "C" void kernel_launch(void* const* d_in, const int* in_sizes, int n_in,
                              void* d_out, int out_size, void* d_ws, size_t ws_size,
                              hipStream_t stream) {
  const float* Q = (const float*)d_in[0];
  const float* K = (const float*)d_in[1];
  const float* V = (const float*)d_in[2];
  float* O = (float*)d_out;
  const size_t need = (OP_ELEMS + ML_ELEMS) * sizeof(float);
  if (ws_size >= need) {
    float* ws = (float*)d_ws;
    hipLaunchKernelGGL(attn_split, dim3(QT, NSPLIT), dim3(256), 0, stream, Q, K, V, ws);
    hipLaunchKernelGGL(attn_combine, dim3(SEQ / 8), dim3(256), 0, stream, ws, O);
  } else {
    hipLaunchKernelGGL(attn_fwd_fb, dim3(SEQ / BR), dim3(256), 0, stream, Q, K, V, O);
  }
}